// Round 12
// baseline (72.949 us; speedup 1.0000x reference)
//
#include <hip/hip_runtime.h>

#define NQ 10
#define DEPTH 4

typedef float f2 __attribute__((ext_vector_type(2)));

__device__ __forceinline__ f2 ff(float a, float b) { f2 r; r.x = a; r.y = b; return r; }
__device__ __forceinline__ f2 fsplat(float a) { return ff(a, a); }
__device__ __forceinline__ f2 rot90(f2 a) { return ff(-a.y, a.x); }   // i * a
__device__ __forceinline__ f2 ffma(f2 a, f2 b, f2 c) { return __builtin_elementwise_fma(a, b, c); }
__device__ __forceinline__ f2 cmul(f2 a, f2 b) { return ffma(fsplat(a.x), b, fsplat(a.y) * rot90(b)); }

// ---------------------------------------------------------------------------
// Compile-time GF(2) frame tracking (validated rounds 2-11).
// Storage index k (10 bits, qubit w <-> bit 9-w); logical index = A k.
// Gate on logical qubit q pairs k and k^v (v = col q of A^-1),
// sign = parity(k & row_q(A)). CNOT rings fold into A entirely.
// ---------------------------------------------------------------------------
struct GateTab {
    unsigned v[DEPTH][NQ];
    unsigned r[DEPTH][NQ];
    unsigned mr[NQ];
};

constexpr GateTab build_tab() {
    GateTab t{};
    unsigned A[NQ], B[NQ];
    for (int p = 0; p < NQ; ++p) { A[p] = 1u << p; B[p] = 1u << p; }
    for (int l = 0; l < DEPTH; ++l) {
        for (int w = 0; w < NQ; ++w) {
            int q = NQ - 1 - w;
            unsigned v = 0;
            for (int p = 0; p < NQ; ++p) v |= ((B[p] >> q) & 1u) << p;
            t.v[l][w] = v;
            t.r[l][w] = A[q];
        }
        int r = (l % (NQ - 1)) + 1;
        for (int w = 0; w < NQ; ++w) {
            int pc = NQ - 1 - w;
            int pt = NQ - 1 - ((w + r) % NQ);
            A[pt] ^= A[pc];
        }
        for (int w = 0; w < NQ; ++w) {
            int pc = NQ - 1 - w;
            int pt = NQ - 1 - ((w + r) % NQ);
            for (int i = 0; i < NQ; ++i) B[i] ^= ((B[i] >> pt) & 1u) << pc;
        }
    }
    for (int i = 0; i < NQ; ++i) t.mr[i] = A[NQ - 1 - i];
    return t;
}
constexpr GateTab TAB = build_tab();

constexpr int msb5(unsigned x) {
    return (x & 16u) ? 4 : (x & 8u) ? 3 : (x & 4u) ? 2 : (x & 2u) ? 1 : 0;
}

// ---------------------------------------------------------------------------
// Cross-lane xor exchange within 32-lane halves (mask 1..31 only).
// Single DPP where one exists (VALU pipe), single ds_swizzle otherwise.
// ---------------------------------------------------------------------------
template<unsigned M>
__device__ __forceinline__ float lxf(float v) {
    static_assert(M > 0u && M < 32u, "mask");
    int x = __float_as_int(v);
    if constexpr (M == 1u)       x = __builtin_amdgcn_update_dpp(x, x, 0xB1,  0xF, 0xF, false); // quad_perm xor1
    else if constexpr (M == 2u)  x = __builtin_amdgcn_update_dpp(x, x, 0x4E,  0xF, 0xF, false); // quad_perm xor2
    else if constexpr (M == 3u)  x = __builtin_amdgcn_update_dpp(x, x, 0x1B,  0xF, 0xF, false); // quad_perm xor3
    else if constexpr (M == 7u)  x = __builtin_amdgcn_update_dpp(x, x, 0x141, 0xF, 0xF, false); // row_half_mirror
    else if constexpr (M == 8u)  x = __builtin_amdgcn_update_dpp(x, x, 0x128, 0xF, 0xF, false); // row_ror:8
    else if constexpr (M == 15u) x = __builtin_amdgcn_update_dpp(x, x, 0x140, 0xF, 0xF, false); // row_mirror
    else                         x = __builtin_amdgcn_ds_swizzle(x, (int)((M << 10) | 0x1Fu));
    return __int_as_float(x);
}
template<unsigned M>
__device__ __forceinline__ f2 exch(f2 v) { return ff(lxf<M>(v.x), lxf<M>(v.y)); }

// ---------------------------------------------------------------------------
// Tangent-form RY gate along frame direction v with sign row r:
//   amp'_k = amp_k + sigma_k * t * amp_{k^v},  t = tan(theta/2),
//   sigma_k = +1 iff parity(k & r).  (True gate = c * this; the per-layer
//   cosine product is folded into the NEXT diag table at qprep time.)
// ---------------------------------------------------------------------------
template<int L, int W>
__device__ __forceinline__ void gate_ry(f2* s, const float* tg, int lane5) {
    constexpr unsigned V = TAB.v[L][W], R = TAB.r[L][W];
    constexpr unsigned VL = V & 31u, VH = V >> 5;
    constexpr unsigned RL = R & 31u, RH = R >> 5;
    constexpr unsigned PVR = (unsigned)(__builtin_popcount(VH & RH) & 1);
    float tp = tg[(L - 1) * NQ + W];           // compile-time index -> SGPR
    if constexpr (RH != 0u) {
        unsigned sg = (unsigned)(__builtin_popcount((unsigned)lane5 & RH) & 1) << 31;
        tp = __uint_as_float(__float_as_uint(tp) ^ sg);
    }
    const float tn = __uint_as_float(__float_as_uint(tp) ^ 0x80000000u);
    if constexpr (VH == 0u) {
        constexpr int PV = 1 << msb5(VL);
        #pragma unroll
        for (int i = 0; i < 32; ++i) {
            if (i & PV) continue;
            const int j = i ^ (int)VL;
            const bool pi = __builtin_popcount((unsigned)i & RL) & 1;
            f2 a = s[i], b = s[j];
            s[i] = ffma(fsplat(pi ? tp : tn), b, a);
            s[j] = ffma(fsplat(pi ? tn : tp), a, b);   // sigma_j = -sigma_i
        }
    } else if constexpr (VL == 0u) {
        #pragma unroll
        for (int i = 0; i < 32; ++i) {
            const bool pi = __builtin_popcount((unsigned)i & RL) & 1;
            f2 p = exch<VH>(s[i]);   // lockstep: pre-update values everywhere
            s[i] = ffma(fsplat(pi ? tp : tn), p, s[i]);
        }
    } else {
        constexpr int PV = 1 << msb5(VL);
        #pragma unroll
        for (int i = 0; i < 32; ++i) {
            if (i & PV) continue;
            const int j = i ^ (int)VL;
            const bool pi = __builtin_popcount((unsigned)i & RL) & 1;
            const bool pj = (!pi) ^ (bool)PVR;   // parity(V&R)==1 identity
            f2 xj = exch<VH>(s[j]);
            f2 xi = exch<VH>(s[i]);
            s[i] = ffma(fsplat(pi ? tp : tn), xj, s[i]);
            s[j] = ffma(fsplat(pj ? tp : tn), xi, s[j]);
        }
    }
}

template<int L, int W> struct Seq {
    static __device__ __forceinline__ void run(f2* s, const float* tg, int lane5) {
        gate_ry<L, W>(s, tg, lane5);
        Seq<L, W + 1>::run(s, tg, lane5);
    }
};
template<int L> struct Seq<L, NQ> {
    static __device__ __forceinline__ void run(f2*, const float*, int) {}
};

// ---------------------------------------------------------------------------
// Workspace: floats [0,40) layer-0 Rot float4 x10; [64,94) RY tangents
// (dense float, gates 10..39); [256,6400) diag tables f2[3][1024] in
// TRANSPOSED coalesced layout: entry for storage k at [gap][(k&31)*32+(k>>5)].
// gap1 table pre-scaled by P1, gap2 by P2*P3 (deferred cosine products).
// ---------------------------------------------------------------------------
__global__ __launch_bounds__(1024) void qprep(const float* __restrict__ qw,
                                              float* __restrict__ ws) {
    const int k = threadIdx.x;
    float4* g0 = (float4*)ws;
    float* tw = ws + 64;
    f2* dg = (f2*)(ws + 256);

    if (k < NQ) {
        float phi = qw[k*3+0], theta = qw[k*3+1], omega = qw[k*3+2];
        float s, c;   sincosf(0.5f * theta, &s, &c);
        float sa, ca; sincosf(0.5f * (phi + omega), &sa, &ca);
        float sb, cb; sincosf(0.5f * (phi - omega), &sb, &cb);
        g0[k] = make_float4(c * ca, -c * sa, -s * cb, -s * sb);
    } else if (k >= 16 && k < 16 + 3 * NQ) {
        int g = k - 6;                          // gate index 10..39
        float theta = qw[g * 3 + 1];
        float s, c; sincosf(0.5f * theta, &s, &c);
        tw[g - 10] = s / c;                     // dense tangent array
    }

    // per-layer cosine products (deferred gate scales)
    float P1 = 1.f, P2 = 1.f, P3 = 1.f;
    #pragma unroll
    for (int w = 0; w < NQ; ++w) {
        P1 *= cosf(0.5f * qw[(1 * NQ + w) * 3 + 1]);
        P2 *= cosf(0.5f * qw[(2 * NQ + w) * 3 + 1]);
        P3 *= cosf(0.5f * qw[(3 * NQ + w) * 3 + 1]);
    }

    // merged diagonal phases: gap0 = phi(L1); gap1 = omega(L1)+phi(L2);
    // gap2 = omega(L2)+phi(L3). omega(L3) dies in |amp|^2.
    float ph0 = 0.f, ph1 = 0.f, ph2 = 0.f;
    #pragma unroll
    for (int w = 0; w < NQ; ++w) {
        const float s1 = (__builtin_popcount((unsigned)k & TAB.r[1][w]) & 1) ? 0.5f : -0.5f;
        const float s2 = (__builtin_popcount((unsigned)k & TAB.r[2][w]) & 1) ? 0.5f : -0.5f;
        const float s3 = (__builtin_popcount((unsigned)k & TAB.r[3][w]) & 1) ? 0.5f : -0.5f;
        ph0 += s1 * qw[(1 * NQ + w) * 3 + 0];
        ph1 += s1 * qw[(1 * NQ + w) * 3 + 2] + s2 * qw[(2 * NQ + w) * 3 + 0];
        ph2 += s2 * qw[(2 * NQ + w) * 3 + 2] + s3 * qw[(3 * NQ + w) * 3 + 0];
    }
    const int tr = (k & 31) * 32 + (k >> 5);    // [loc][lane5] transposed
    float s, c;
    sincosf(ph0, &s, &c); dg[0 * 1024 + tr] = ff(c, s);
    sincosf(ph1, &s, &c); dg[1 * 1024 + tr] = ff(c * P1, s * P1);
    const float p23 = P2 * P3;
    sincosf(ph2, &s, &c); dg[2 * 1024 + tr] = ff(c * p23, s * p23);
}

// apply one merged diagonal from global (coalesced: lane l5 reads entry
// i*32+l5, consecutive lanes adjacent 8B; table is L2-resident, VMEM pipe idle)
__device__ __forceinline__ void apply_diag(f2* s, const f2* __restrict__ base) {
    #pragma unroll
    for (int i = 0; i < 32; ++i) s[i] = cmul(base[i * 32], s[i]);
}

// ---------------------------------------------------------------------------
// One wave simulates TWO batch elements: element = lane bit 5.
// Within a 32-lane half: storage k = (lane5 << 5) | loc.
//   qubits 0..4 <-> lane5 bits 4..0 ; qubits 5..9 <-> loc bits 4..0.
// 32 f2 amps per lane (64 floats) — MUST be architected-VGPR resident:
// launch_bounds(256,2) lifts the 128-reg cap so the allocator doesn't park
// the state in AGPRs (R11 post-mortem: accvgpr shuttle ≈ +3k instrs/wave).
// ---------------------------------------------------------------------------
__global__ __launch_bounds__(256, 2) void qsim_kernel(
        const float* __restrict__ inp,
        const float* __restrict__ ws,
        float* __restrict__ out,
        int B) {
    const int tid = threadIdx.x;
    const int lane = tid & 63;
    const int lane5 = lane & 31;
    const int e = lane >> 5;
    int b0 = ((blockIdx.x << 2) | (tid >> 6)) << 1;
    b0 = __builtin_amdgcn_readfirstlane(b0);
    if (b0 >= B) return;
    const int b = b0 + e;

    const float4* g0 = (const float4*)ws;
    const float* tw = ws + 64;
    const f2* dg = (const f2*)(ws + 256);

    // ---- hoist all 30 tangents into SGPRs (latency hidden under preamble) ----
    float tg[3 * NQ];
    #pragma unroll
    for (int g = 0; g < 3 * NQ; ++g)
        tg[g] = __int_as_float(__builtin_amdgcn_readfirstlane(__float_as_int(tw[g])));

    // ---- embedding fused with layer-0 Rot: lane w<10 of each half computes
    // qubit w of its element ----
    float x = (lane5 < NQ && b < B) ? inp[b * NQ + lane5] : 0.0f;
    float sn, cn;
    sincosf(0.5f * x, &sn, &cn);
    float a0r = 0.f, a0i = 0.f, a1r = 0.f, a1i = 0.f;
    if (lane5 < NQ) {
        float4 mm = g0[lane5];
        a0r = mm.x * cn + mm.z * sn;
        a0i = mm.y * cn + mm.w * sn;
        a1r = -mm.z * cn + mm.x * sn;
        a1i =  mm.w * cn - mm.y * sn;
    }
    // lane factor: qubits 0..4 <-> lane5 bits 4..0 (broadcast within half)
    f2 L;
    {
        float r0 = __shfl(a0r, 0, 32), i0 = __shfl(a0i, 0, 32);
        float r1 = __shfl(a1r, 0, 32), i1 = __shfl(a1i, 0, 32);
        int bit = (lane5 >> 4) & 1;
        L = ff(bit ? r1 : r0, bit ? i1 : i0);
    }
    #pragma unroll
    for (int w = 1; w < 5; ++w) {
        float r0 = __shfl(a0r, w, 32), i0 = __shfl(a0i, w, 32);
        float r1 = __shfl(a1r, w, 32), i1 = __shfl(a1i, w, 32);
        int bit = (lane5 >> (4 - w)) & 1;
        L = cmul(L, ff(bit ? r1 : r0, bit ? i1 : i0));
    }
    // local factors: qubits 5..9 <-> loc bits 4..0
    f2 A0[5], A1[5];
    #pragma unroll
    for (int j = 0; j < 5; ++j) {
        A0[j] = ff(__shfl(a0r, 5 + j, 32), __shfl(a0i, 5 + j, 32));
        A1[j] = ff(__shfl(a1r, 5 + j, 32), __shfl(a1i, 5 + j, 32));
    }
    f2 s[32];
    {
        f2 t01[4], t23[4], t3[8], lt[4];
        #pragma unroll
        for (int i = 0; i < 4; ++i) {
            t01[i] = cmul((i & 2) ? A1[0] : A0[0], (i & 1) ? A1[1] : A0[1]);
            t23[i] = cmul((i & 2) ? A1[2] : A0[2], (i & 1) ? A1[3] : A0[3]);
        }
        #pragma unroll
        for (int i = 0; i < 8; ++i)
            t3[i] = cmul(t23[i >> 1], (i & 1) ? A1[4] : A0[4]);
        #pragma unroll
        for (int i = 0; i < 4; ++i) lt[i] = cmul(L, t01[i]);
        #pragma unroll
        for (int i = 0; i < 32; ++i) s[i] = cmul(lt[i >> 3], t3[i & 7]);
    }

    // ---- D(phi1) ; RY1(t) ; D(w1+phi2)*P1 ; RY2(t) ; D(w2+phi3)*P2*P3 ; RY3(t) ----
    apply_diag(s, dg + lane5);
    Seq<1, 0>::run(s, tg, lane5);
    apply_diag(s, dg + 1024 + lane5);
    Seq<2, 0>::run(s, tg, lane5);
    apply_diag(s, dg + 2048 + lane5);
    Seq<3, 0>::run(s, tg, lane5);
    // omega(L3) diagonal dropped: killed by |amp|^2. Cosine products folded
    // into the diag tables -> state here is exactly the true state.

    // ---- measurement: local 32-pt WHT, then signed 5-level lane butterflies --
    float F[32];
    #pragma unroll
    for (int i = 0; i < 32; ++i) { f2 t = s[i] * s[i]; F[i] = t.x + t.y; }
    #pragma unroll
    for (int bit = 1; bit < 32; bit <<= 1) {
        #pragma unroll
        for (int i = 0; i < 32; ++i)
            if (!(i & bit)) { float u = F[i], v = F[i | bit]; F[i] = u + v; F[i | bit] = u - v; }
    }
    float ow = 0.0f;
    #pragma unroll
    for (int qi = 0; qi < NQ; ++qi) {
        const unsigned m = TAB.mr[qi];
        const unsigned ml = m & 31u, mh = m >> 5;
        float v = F[ml];
        if (mh) {
            unsigned sg = (unsigned)(__builtin_popcount((unsigned)lane5 & mh) & 1) << 31;
            v = __uint_as_float(__float_as_uint(v) ^ sg);
        }
        v += lxf<1u>(v); v += lxf<2u>(v); v += lxf<4u>(v);
        v += lxf<8u>(v); v += lxf<16u>(v);
        ow = (lane5 == qi) ? v : ow;
    }
    if (lane5 < NQ && b < B) out[b * NQ + lane5] = ow;
}

extern "C" void kernel_launch(void* const* d_in, const int* in_sizes, int n_in,
                              void* d_out, int out_size, void* d_ws, size_t ws_size,
                              hipStream_t stream) {
    const float* inp = (const float*)d_in[0];       // (B, NQ) float32
    const float* qw  = (const float*)d_in[1];       // (DEPTH, NQ, 3) float32
    float* out = (float*)d_out;                     // (B, NQ) float32
    float* ws  = (float*)d_ws;

    const int B = in_sizes[0] / NQ;

    qprep<<<1, 1024, 0, stream>>>(qw, ws);
    qsim_kernel<<<(B + 7) / 8, 256, 0, stream>>>(inp, ws, out, B);
}

// Round 13
// 71.341 us; speedup vs baseline: 1.0225x; 1.0225x over previous
//
#include <hip/hip_runtime.h>

#define NQ 10
#define DEPTH 4

typedef float f2 __attribute__((ext_vector_type(2)));

__device__ __forceinline__ f2 ff(float a, float b) { f2 r; r.x = a; r.y = b; return r; }
__device__ __forceinline__ f2 fsplat(float a) { return ff(a, a); }
__device__ __forceinline__ f2 rot90(f2 a) { return ff(-a.y, a.x); }   // i * a
__device__ __forceinline__ f2 ffma(f2 a, f2 b, f2 c) { return __builtin_elementwise_fma(a, b, c); }
__device__ __forceinline__ f2 cmul(f2 a, f2 b) { return ffma(fsplat(a.x), b, fsplat(a.y) * rot90(b)); }

// ---------------------------------------------------------------------------
// Compile-time GF(2) frame tracking (validated rounds 2-12).
// Storage index k (10 bits, qubit w <-> bit 9-w); logical index = A k.
// Gate on logical qubit q pairs k and k^v (v = col q of A^-1),
// sign = parity(k & row_q(A)). CNOT rings fold into A entirely.
// ---------------------------------------------------------------------------
struct GateTab {
    unsigned v[DEPTH][NQ];
    unsigned r[DEPTH][NQ];
    unsigned mr[NQ];
};

constexpr GateTab build_tab() {
    GateTab t{};
    unsigned A[NQ], B[NQ];
    for (int p = 0; p < NQ; ++p) { A[p] = 1u << p; B[p] = 1u << p; }
    for (int l = 0; l < DEPTH; ++l) {
        for (int w = 0; w < NQ; ++w) {
            int q = NQ - 1 - w;
            unsigned v = 0;
            for (int p = 0; p < NQ; ++p) v |= ((B[p] >> q) & 1u) << p;
            t.v[l][w] = v;
            t.r[l][w] = A[q];
        }
        int r = (l % (NQ - 1)) + 1;
        for (int w = 0; w < NQ; ++w) {
            int pc = NQ - 1 - w;
            int pt = NQ - 1 - ((w + r) % NQ);
            A[pt] ^= A[pc];
        }
        for (int w = 0; w < NQ; ++w) {
            int pc = NQ - 1 - w;
            int pt = NQ - 1 - ((w + r) % NQ);
            for (int i = 0; i < NQ; ++i) B[i] ^= ((B[i] >> pt) & 1u) << pc;
        }
    }
    for (int i = 0; i < NQ; ++i) t.mr[i] = A[NQ - 1 - i];
    return t;
}
constexpr GateTab TAB = build_tab();

constexpr int msb5(unsigned x) {
    return (x & 16u) ? 4 : (x & 8u) ? 3 : (x & 4u) ? 2 : (x & 2u) ? 1 : 0;
}

// ---------------------------------------------------------------------------
// Cross-lane xor exchange within 32-lane halves (mask 1..31 only).
// Single DPP where one exists (VALU pipe), single ds_swizzle otherwise.
// NOTE: DPP/swizzle operands must be arch VGPRs — keeping total register
// demand <=128 (see apply_diag chunking) prevents AGPR parking + shuttles.
// ---------------------------------------------------------------------------
template<unsigned M>
__device__ __forceinline__ float lxf(float v) {
    static_assert(M > 0u && M < 32u, "mask");
    int x = __float_as_int(v);
    if constexpr (M == 1u)       x = __builtin_amdgcn_update_dpp(x, x, 0xB1,  0xF, 0xF, false); // quad_perm xor1
    else if constexpr (M == 2u)  x = __builtin_amdgcn_update_dpp(x, x, 0x4E,  0xF, 0xF, false); // quad_perm xor2
    else if constexpr (M == 3u)  x = __builtin_amdgcn_update_dpp(x, x, 0x1B,  0xF, 0xF, false); // quad_perm xor3
    else if constexpr (M == 7u)  x = __builtin_amdgcn_update_dpp(x, x, 0x141, 0xF, 0xF, false); // row_half_mirror
    else if constexpr (M == 8u)  x = __builtin_amdgcn_update_dpp(x, x, 0x128, 0xF, 0xF, false); // row_ror:8
    else if constexpr (M == 15u) x = __builtin_amdgcn_update_dpp(x, x, 0x140, 0xF, 0xF, false); // row_mirror
    else                         x = __builtin_amdgcn_ds_swizzle(x, (int)((M << 10) | 0x1Fu));
    return __int_as_float(x);
}
template<unsigned M>
__device__ __forceinline__ f2 exch(f2 v) { return ff(lxf<M>(v.x), lxf<M>(v.y)); }

// ---------------------------------------------------------------------------
// Tangent-form RY gate along frame direction v with sign row r:
//   amp'_k = amp_k + sigma_k * t * amp_{k^v},  t = tan(theta/2),
//   sigma_k = +1 iff parity(k & r).  (True gate = c * this; the per-layer
//   cosine product is folded into the NEXT diag table at qprep time.)
// ---------------------------------------------------------------------------
template<int L, int W>
__device__ __forceinline__ void gate_ry(f2* s, const float* tg, int lane5) {
    constexpr unsigned V = TAB.v[L][W], R = TAB.r[L][W];
    constexpr unsigned VL = V & 31u, VH = V >> 5;
    constexpr unsigned RL = R & 31u, RH = R >> 5;
    constexpr unsigned PVR = (unsigned)(__builtin_popcount(VH & RH) & 1);
    float tp = tg[(L - 1) * NQ + W];           // compile-time index -> SGPR
    if constexpr (RH != 0u) {
        unsigned sg = (unsigned)(__builtin_popcount((unsigned)lane5 & RH) & 1) << 31;
        tp = __uint_as_float(__float_as_uint(tp) ^ sg);
    }
    const float tn = __uint_as_float(__float_as_uint(tp) ^ 0x80000000u);
    if constexpr (VH == 0u) {
        constexpr int PV = 1 << msb5(VL);
        #pragma unroll
        for (int i = 0; i < 32; ++i) {
            if (i & PV) continue;
            const int j = i ^ (int)VL;
            const bool pi = __builtin_popcount((unsigned)i & RL) & 1;
            f2 a = s[i], b = s[j];
            s[i] = ffma(fsplat(pi ? tp : tn), b, a);
            s[j] = ffma(fsplat(pi ? tn : tp), a, b);   // sigma_j = -sigma_i
        }
    } else if constexpr (VL == 0u) {
        #pragma unroll
        for (int i = 0; i < 32; ++i) {
            const bool pi = __builtin_popcount((unsigned)i & RL) & 1;
            f2 p = exch<VH>(s[i]);   // lockstep: pre-update values everywhere
            s[i] = ffma(fsplat(pi ? tp : tn), p, s[i]);
        }
    } else {
        constexpr int PV = 1 << msb5(VL);
        #pragma unroll
        for (int i = 0; i < 32; ++i) {
            if (i & PV) continue;
            const int j = i ^ (int)VL;
            const bool pi = __builtin_popcount((unsigned)i & RL) & 1;
            const bool pj = (!pi) ^ (bool)PVR;   // parity(V&R)==1 identity
            f2 xj = exch<VH>(s[j]);
            f2 xi = exch<VH>(s[i]);
            s[i] = ffma(fsplat(pi ? tp : tn), xj, s[i]);
            s[j] = ffma(fsplat(pj ? tp : tn), xi, s[j]);
        }
    }
}

template<int L, int W> struct Seq {
    static __device__ __forceinline__ void run(f2* s, const float* tg, int lane5) {
        gate_ry<L, W>(s, tg, lane5);
        Seq<L, W + 1>::run(s, tg, lane5);
    }
};
template<int L> struct Seq<L, NQ> {
    static __device__ __forceinline__ void run(f2*, const float*, int) {}
};

// ---------------------------------------------------------------------------
// Workspace: floats [0,40) layer-0 Rot float4 x10; [64,94) RY tangents
// (dense float, gates 10..39); [256,6400) diag tables f2[3][1024] in
// TRANSPOSED coalesced layout: entry for storage k at [gap][(k&31)*32+(k>>5)].
// gap1 table pre-scaled by P1, gap2 by P2*P3 (deferred cosine products).
// ---------------------------------------------------------------------------
__global__ __launch_bounds__(1024) void qprep(const float* __restrict__ qw,
                                              float* __restrict__ ws) {
    const int k = threadIdx.x;
    float4* g0 = (float4*)ws;
    float* tw = ws + 64;
    f2* dg = (f2*)(ws + 256);

    if (k < NQ) {
        float phi = qw[k*3+0], theta = qw[k*3+1], omega = qw[k*3+2];
        float s, c;   sincosf(0.5f * theta, &s, &c);
        float sa, ca; sincosf(0.5f * (phi + omega), &sa, &ca);
        float sb, cb; sincosf(0.5f * (phi - omega), &sb, &cb);
        g0[k] = make_float4(c * ca, -c * sa, -s * cb, -s * sb);
    } else if (k >= 16 && k < 16 + 3 * NQ) {
        int g = k - 6;                          // gate index 10..39
        float theta = qw[g * 3 + 1];
        float s, c; sincosf(0.5f * theta, &s, &c);
        tw[g - 10] = s / c;                     // dense tangent array
    }

    // per-layer cosine products (deferred gate scales)
    float P1 = 1.f, P2 = 1.f, P3 = 1.f;
    #pragma unroll
    for (int w = 0; w < NQ; ++w) {
        P1 *= cosf(0.5f * qw[(1 * NQ + w) * 3 + 1]);
        P2 *= cosf(0.5f * qw[(2 * NQ + w) * 3 + 1]);
        P3 *= cosf(0.5f * qw[(3 * NQ + w) * 3 + 1]);
    }

    // merged diagonal phases: gap0 = phi(L1); gap1 = omega(L1)+phi(L2);
    // gap2 = omega(L2)+phi(L3). omega(L3) dies in |amp|^2.
    float ph0 = 0.f, ph1 = 0.f, ph2 = 0.f;
    #pragma unroll
    for (int w = 0; w < NQ; ++w) {
        const float s1 = (__builtin_popcount((unsigned)k & TAB.r[1][w]) & 1) ? 0.5f : -0.5f;
        const float s2 = (__builtin_popcount((unsigned)k & TAB.r[2][w]) & 1) ? 0.5f : -0.5f;
        const float s3 = (__builtin_popcount((unsigned)k & TAB.r[3][w]) & 1) ? 0.5f : -0.5f;
        ph0 += s1 * qw[(1 * NQ + w) * 3 + 0];
        ph1 += s1 * qw[(1 * NQ + w) * 3 + 2] + s2 * qw[(2 * NQ + w) * 3 + 0];
        ph2 += s2 * qw[(2 * NQ + w) * 3 + 2] + s3 * qw[(3 * NQ + w) * 3 + 0];
    }
    const int tr = (k & 31) * 32 + (k >> 5);    // [loc][lane5] transposed
    float s, c;
    sincosf(ph0, &s, &c); dg[0 * 1024 + tr] = ff(c, s);
    sincosf(ph1, &s, &c); dg[1 * 1024 + tr] = ff(c * P1, s * P1);
    const float p23 = P2 * P3;
    sincosf(ph2, &s, &c); dg[2 * 1024 + tr] = ff(c * p23, s * p23);
}

// ---------------------------------------------------------------------------
// Apply one merged diagonal from global, CHUNKED 4x8 with anti-hoist fences:
// peak live diag values = 16 floats (was 64 when the compiler hoisted all 32
// loads). Keeps whole-kernel register demand <=128 -> all-arch-VGPR, no AGPR
// shuttles around DPP/swizzle, higher occupancy. Loads stay L2-resident.
// ---------------------------------------------------------------------------
__device__ __forceinline__ void apply_diag(f2* s, const f2* __restrict__ base) {
    #pragma unroll
    for (int c = 0; c < 4; ++c) {
        f2 d[8];
        #pragma unroll
        for (int i = 0; i < 8; ++i) d[i] = base[(c * 8 + i) * 32];
        #pragma unroll
        for (int i = 0; i < 8; ++i) s[c * 8 + i] = cmul(d[i], s[c * 8 + i]);
        asm volatile("" ::: "memory");   // fence: don't hoist next chunk's loads
    }
}

// ---------------------------------------------------------------------------
// One wave simulates TWO batch elements: element = lane bit 5.
// Within a 32-lane half: storage k = (lane5 << 5) | loc.
//   qubits 0..4 <-> lane5 bits 4..0 ; qubits 5..9 <-> loc bits 4..0.
// 32 f2 amps per lane. All exchanges have mask < 32 (no bpermute anywhere).
// ---------------------------------------------------------------------------
__global__ __launch_bounds__(256, 4) void qsim_kernel(
        const float* __restrict__ inp,
        const float* __restrict__ ws,
        float* __restrict__ out,
        int B) {
    const int tid = threadIdx.x;
    const int lane = tid & 63;
    const int lane5 = lane & 31;
    const int e = lane >> 5;
    int b0 = ((blockIdx.x << 2) | (tid >> 6)) << 1;
    b0 = __builtin_amdgcn_readfirstlane(b0);
    if (b0 >= B) return;
    const int b = b0 + e;

    const float4* g0 = (const float4*)ws;
    const float* tw = ws + 64;
    const f2* dg = (const f2*)(ws + 256);

    // ---- hoist all 30 tangents into SGPRs (latency hidden under preamble) ----
    float tg[3 * NQ];
    #pragma unroll
    for (int g = 0; g < 3 * NQ; ++g)
        tg[g] = __int_as_float(__builtin_amdgcn_readfirstlane(__float_as_int(tw[g])));

    // ---- embedding fused with layer-0 Rot: lane w<10 of each half computes
    // qubit w of its element ----
    float x = (lane5 < NQ && b < B) ? inp[b * NQ + lane5] : 0.0f;
    float sn, cn;
    sincosf(0.5f * x, &sn, &cn);
    float a0r = 0.f, a0i = 0.f, a1r = 0.f, a1i = 0.f;
    if (lane5 < NQ) {
        float4 mm = g0[lane5];
        a0r = mm.x * cn + mm.z * sn;
        a0i = mm.y * cn + mm.w * sn;
        a1r = -mm.z * cn + mm.x * sn;
        a1i =  mm.w * cn - mm.y * sn;
    }
    // lane factor: qubits 0..4 <-> lane5 bits 4..0 (broadcast within half)
    f2 L;
    {
        float r0 = __shfl(a0r, 0, 32), i0 = __shfl(a0i, 0, 32);
        float r1 = __shfl(a1r, 0, 32), i1 = __shfl(a1i, 0, 32);
        int bit = (lane5 >> 4) & 1;
        L = ff(bit ? r1 : r0, bit ? i1 : i0);
    }
    #pragma unroll
    for (int w = 1; w < 5; ++w) {
        float r0 = __shfl(a0r, w, 32), i0 = __shfl(a0i, w, 32);
        float r1 = __shfl(a1r, w, 32), i1 = __shfl(a1i, w, 32);
        int bit = (lane5 >> (4 - w)) & 1;
        L = cmul(L, ff(bit ? r1 : r0, bit ? i1 : i0));
    }
    // local factors: qubits 5..9 <-> loc bits 4..0
    f2 A0[5], A1[5];
    #pragma unroll
    for (int j = 0; j < 5; ++j) {
        A0[j] = ff(__shfl(a0r, 5 + j, 32), __shfl(a0i, 5 + j, 32));
        A1[j] = ff(__shfl(a1r, 5 + j, 32), __shfl(a1i, 5 + j, 32));
    }
    f2 s[32];
    {
        f2 t01[4], t23[4], t3[8], lt[4];
        #pragma unroll
        for (int i = 0; i < 4; ++i) {
            t01[i] = cmul((i & 2) ? A1[0] : A0[0], (i & 1) ? A1[1] : A0[1]);
            t23[i] = cmul((i & 2) ? A1[2] : A0[2], (i & 1) ? A1[3] : A0[3]);
        }
        #pragma unroll
        for (int i = 0; i < 8; ++i)
            t3[i] = cmul(t23[i >> 1], (i & 1) ? A1[4] : A0[4]);
        #pragma unroll
        for (int i = 0; i < 4; ++i) lt[i] = cmul(L, t01[i]);
        #pragma unroll
        for (int i = 0; i < 32; ++i) s[i] = cmul(lt[i >> 3], t3[i & 7]);
    }

    // ---- D(phi1) ; RY1(t) ; D(w1+phi2)*P1 ; RY2(t) ; D(w2+phi3)*P2*P3 ; RY3(t) ----
    apply_diag(s, dg + lane5);
    Seq<1, 0>::run(s, tg, lane5);
    apply_diag(s, dg + 1024 + lane5);
    Seq<2, 0>::run(s, tg, lane5);
    apply_diag(s, dg + 2048 + lane5);
    Seq<3, 0>::run(s, tg, lane5);
    // omega(L3) diagonal dropped: killed by |amp|^2. Cosine products folded
    // into the diag tables -> state here is exactly the true state.

    // ---- measurement: local 32-pt WHT, then signed 5-level lane butterflies --
    float F[32];
    #pragma unroll
    for (int i = 0; i < 32; ++i) { f2 t = s[i] * s[i]; F[i] = t.x + t.y; }
    #pragma unroll
    for (int bit = 1; bit < 32; bit <<= 1) {
        #pragma unroll
        for (int i = 0; i < 32; ++i)
            if (!(i & bit)) { float u = F[i], v = F[i | bit]; F[i] = u + v; F[i | bit] = u - v; }
    }
    float ow = 0.0f;
    #pragma unroll
    for (int qi = 0; qi < NQ; ++qi) {
        const unsigned m = TAB.mr[qi];
        const unsigned ml = m & 31u, mh = m >> 5;
        float v = F[ml];
        if (mh) {
            unsigned sg = (unsigned)(__builtin_popcount((unsigned)lane5 & mh) & 1) << 31;
            v = __uint_as_float(__float_as_uint(v) ^ sg);
        }
        v += lxf<1u>(v); v += lxf<2u>(v); v += lxf<4u>(v);
        v += lxf<8u>(v); v += lxf<16u>(v);
        ow = (lane5 == qi) ? v : ow;
    }
    if (lane5 < NQ && b < B) out[b * NQ + lane5] = ow;
}

extern "C" void kernel_launch(void* const* d_in, const int* in_sizes, int n_in,
                              void* d_out, int out_size, void* d_ws, size_t ws_size,
                              hipStream_t stream) {
    const float* inp = (const float*)d_in[0];       // (B, NQ) float32
    const float* qw  = (const float*)d_in[1];       // (DEPTH, NQ, 3) float32
    float* out = (float*)d_out;                     // (B, NQ) float32
    float* ws  = (float*)d_ws;

    const int B = in_sizes[0] / NQ;

    qprep<<<1, 1024, 0, stream>>>(qw, ws);
    qsim_kernel<<<(B + 7) / 8, 256, 0, stream>>>(inp, ws, out, B);
}

// Round 14
// 71.218 us; speedup vs baseline: 1.0243x; 1.0017x over previous
//
#include <hip/hip_runtime.h>

#define NQ 10
#define DEPTH 4

typedef float f2 __attribute__((ext_vector_type(2)));

__device__ __forceinline__ f2 ff(float a, float b) { f2 r; r.x = a; r.y = b; return r; }
__device__ __forceinline__ f2 fsplat(float a) { return ff(a, a); }
__device__ __forceinline__ f2 rot90(f2 a) { return ff(-a.y, a.x); }   // i * a
__device__ __forceinline__ f2 ffma(f2 a, f2 b, f2 c) { return __builtin_elementwise_fma(a, b, c); }
__device__ __forceinline__ f2 cmul(f2 a, f2 b) { return ffma(fsplat(a.x), b, fsplat(a.y) * rot90(b)); }

// ---------------------------------------------------------------------------
// Compile-time GF(2) frame tracking (validated rounds 2-12).
// Storage index k (10 bits, qubit w <-> bit 9-w); logical index = A k.
// Gate on logical qubit q pairs k and k^v (v = col q of A^-1),
// sign = parity(k & row_q(A)). CNOT rings fold into A entirely.
// ---------------------------------------------------------------------------
struct GateTab {
    unsigned v[DEPTH][NQ];
    unsigned r[DEPTH][NQ];
    unsigned mr[NQ];
};

constexpr GateTab build_tab() {
    GateTab t{};
    unsigned A[NQ], B[NQ];
    for (int p = 0; p < NQ; ++p) { A[p] = 1u << p; B[p] = 1u << p; }
    for (int l = 0; l < DEPTH; ++l) {
        for (int w = 0; w < NQ; ++w) {
            int q = NQ - 1 - w;
            unsigned v = 0;
            for (int p = 0; p < NQ; ++p) v |= ((B[p] >> q) & 1u) << p;
            t.v[l][w] = v;
            t.r[l][w] = A[q];
        }
        int r = (l % (NQ - 1)) + 1;
        for (int w = 0; w < NQ; ++w) {
            int pc = NQ - 1 - w;
            int pt = NQ - 1 - ((w + r) % NQ);
            A[pt] ^= A[pc];
        }
        for (int w = 0; w < NQ; ++w) {
            int pc = NQ - 1 - w;
            int pt = NQ - 1 - ((w + r) % NQ);
            for (int i = 0; i < NQ; ++i) B[i] ^= ((B[i] >> pt) & 1u) << pc;
        }
    }
    for (int i = 0; i < NQ; ++i) t.mr[i] = A[NQ - 1 - i];
    return t;
}
constexpr GateTab TAB = build_tab();

constexpr int msb5(unsigned x) {
    return (x & 16u) ? 4 : (x & 8u) ? 3 : (x & 4u) ? 2 : (x & 2u) ? 1 : 0;
}

// ---------------------------------------------------------------------------
// Cross-lane xor exchange within 32-lane halves (mask 1..31 only).
// Single DPP where one exists (VALU pipe), single ds_swizzle otherwise.
// NOTE: DPP/swizzle operands must be arch VGPRs — keeping total register
// demand <=128 (see apply_diag chunking) prevents AGPR parking + shuttles.
// ---------------------------------------------------------------------------
template<unsigned M>
__device__ __forceinline__ float lxf(float v) {
    static_assert(M > 0u && M < 32u, "mask");
    int x = __float_as_int(v);
    if constexpr (M == 1u)       x = __builtin_amdgcn_update_dpp(x, x, 0xB1,  0xF, 0xF, false); // quad_perm xor1
    else if constexpr (M == 2u)  x = __builtin_amdgcn_update_dpp(x, x, 0x4E,  0xF, 0xF, false); // quad_perm xor2
    else if constexpr (M == 3u)  x = __builtin_amdgcn_update_dpp(x, x, 0x1B,  0xF, 0xF, false); // quad_perm xor3
    else if constexpr (M == 7u)  x = __builtin_amdgcn_update_dpp(x, x, 0x141, 0xF, 0xF, false); // row_half_mirror
    else if constexpr (M == 8u)  x = __builtin_amdgcn_update_dpp(x, x, 0x128, 0xF, 0xF, false); // row_ror:8
    else if constexpr (M == 15u) x = __builtin_amdgcn_update_dpp(x, x, 0x140, 0xF, 0xF, false); // row_mirror
    else                         x = __builtin_amdgcn_ds_swizzle(x, (int)((M << 10) | 0x1Fu));
    return __int_as_float(x);
}
template<unsigned M>
__device__ __forceinline__ f2 exch(f2 v) { return ff(lxf<M>(v.x), lxf<M>(v.y)); }

// ---------------------------------------------------------------------------
// Tangent-form RY gate along frame direction v with sign row r:
//   amp'_k = amp_k + sigma_k * t * amp_{k^v},  t = tan(theta/2),
//   sigma_k = +1 iff parity(k & r).  (True gate = c * this; the per-layer
//   cosine product is folded into the NEXT diag table at qprep time.)
// ---------------------------------------------------------------------------
template<int L, int W>
__device__ __forceinline__ void gate_ry(f2* s, const float* tg, int lane5) {
    constexpr unsigned V = TAB.v[L][W], R = TAB.r[L][W];
    constexpr unsigned VL = V & 31u, VH = V >> 5;
    constexpr unsigned RL = R & 31u, RH = R >> 5;
    constexpr unsigned PVR = (unsigned)(__builtin_popcount(VH & RH) & 1);
    float tp = tg[(L - 1) * NQ + W];           // compile-time index -> SGPR
    if constexpr (RH != 0u) {
        unsigned sg = (unsigned)(__builtin_popcount((unsigned)lane5 & RH) & 1) << 31;
        tp = __uint_as_float(__float_as_uint(tp) ^ sg);
    }
    const float tn = __uint_as_float(__float_as_uint(tp) ^ 0x80000000u);
    if constexpr (VH == 0u) {
        constexpr int PV = 1 << msb5(VL);
        #pragma unroll
        for (int i = 0; i < 32; ++i) {
            if (i & PV) continue;
            const int j = i ^ (int)VL;
            const bool pi = __builtin_popcount((unsigned)i & RL) & 1;
            f2 a = s[i], b = s[j];
            s[i] = ffma(fsplat(pi ? tp : tn), b, a);
            s[j] = ffma(fsplat(pi ? tn : tp), a, b);   // sigma_j = -sigma_i
        }
    } else if constexpr (VL == 0u) {
        #pragma unroll
        for (int i = 0; i < 32; ++i) {
            const bool pi = __builtin_popcount((unsigned)i & RL) & 1;
            f2 p = exch<VH>(s[i]);   // lockstep: pre-update values everywhere
            s[i] = ffma(fsplat(pi ? tp : tn), p, s[i]);
        }
    } else {
        constexpr int PV = 1 << msb5(VL);
        #pragma unroll
        for (int i = 0; i < 32; ++i) {
            if (i & PV) continue;
            const int j = i ^ (int)VL;
            const bool pi = __builtin_popcount((unsigned)i & RL) & 1;
            const bool pj = (!pi) ^ (bool)PVR;   // parity(V&R)==1 identity
            f2 xj = exch<VH>(s[j]);
            f2 xi = exch<VH>(s[i]);
            s[i] = ffma(fsplat(pi ? tp : tn), xj, s[i]);
            s[j] = ffma(fsplat(pj ? tp : tn), xi, s[j]);
        }
    }
}

template<int L, int W> struct Seq {
    static __device__ __forceinline__ void run(f2* s, const float* tg, int lane5) {
        gate_ry<L, W>(s, tg, lane5);
        Seq<L, W + 1>::run(s, tg, lane5);
    }
};
template<int L> struct Seq<L, NQ> {
    static __device__ __forceinline__ void run(f2*, const float*, int) {}
};

// ---------------------------------------------------------------------------
// Workspace: floats [0,40) layer-0 Rot float4 x10; [64,94) RY tangents
// (dense float, gates 10..39); [256,6400) diag tables f2[3][1024] in
// TRANSPOSED coalesced layout: entry for storage k at [gap][(k&31)*32+(k>>5)].
// gap1 table pre-scaled by P1, gap2 by P2*P3 (deferred cosine products).
// ---------------------------------------------------------------------------
__global__ __launch_bounds__(1024) void qprep(const float* __restrict__ qw,
                                              float* __restrict__ ws) {
    const int k = threadIdx.x;
    float4* g0 = (float4*)ws;
    float* tw = ws + 64;
    f2* dg = (f2*)(ws + 256);

    if (k < NQ) {
        float phi = qw[k*3+0], theta = qw[k*3+1], omega = qw[k*3+2];
        float s, c;   sincosf(0.5f * theta, &s, &c);
        float sa, ca; sincosf(0.5f * (phi + omega), &sa, &ca);
        float sb, cb; sincosf(0.5f * (phi - omega), &sb, &cb);
        g0[k] = make_float4(c * ca, -c * sa, -s * cb, -s * sb);
    } else if (k >= 16 && k < 16 + 3 * NQ) {
        int g = k - 6;                          // gate index 10..39
        float theta = qw[g * 3 + 1];
        float s, c; sincosf(0.5f * theta, &s, &c);
        tw[g - 10] = s / c;                     // dense tangent array
    }

    // per-layer cosine products (deferred gate scales)
    float P1 = 1.f, P2 = 1.f, P3 = 1.f;
    #pragma unroll
    for (int w = 0; w < NQ; ++w) {
        P1 *= cosf(0.5f * qw[(1 * NQ + w) * 3 + 1]);
        P2 *= cosf(0.5f * qw[(2 * NQ + w) * 3 + 1]);
        P3 *= cosf(0.5f * qw[(3 * NQ + w) * 3 + 1]);
    }

    // merged diagonal phases: gap0 = phi(L1); gap1 = omega(L1)+phi(L2);
    // gap2 = omega(L2)+phi(L3). omega(L3) dies in |amp|^2.
    float ph0 = 0.f, ph1 = 0.f, ph2 = 0.f;
    #pragma unroll
    for (int w = 0; w < NQ; ++w) {
        const float s1 = (__builtin_popcount((unsigned)k & TAB.r[1][w]) & 1) ? 0.5f : -0.5f;
        const float s2 = (__builtin_popcount((unsigned)k & TAB.r[2][w]) & 1) ? 0.5f : -0.5f;
        const float s3 = (__builtin_popcount((unsigned)k & TAB.r[3][w]) & 1) ? 0.5f : -0.5f;
        ph0 += s1 * qw[(1 * NQ + w) * 3 + 0];
        ph1 += s1 * qw[(1 * NQ + w) * 3 + 2] + s2 * qw[(2 * NQ + w) * 3 + 0];
        ph2 += s2 * qw[(2 * NQ + w) * 3 + 2] + s3 * qw[(3 * NQ + w) * 3 + 0];
    }
    const int tr = (k & 31) * 32 + (k >> 5);    // [loc][lane5] transposed
    float s, c;
    sincosf(ph0, &s, &c); dg[0 * 1024 + tr] = ff(c, s);
    sincosf(ph1, &s, &c); dg[1 * 1024 + tr] = ff(c * P1, s * P1);
    const float p23 = P2 * P3;
    sincosf(ph2, &s, &c); dg[2 * 1024 + tr] = ff(c * p23, s * p23);
}

// ---------------------------------------------------------------------------
// Apply one merged diagonal from global, CHUNKED 4x8 with anti-hoist fences:
// peak live diag values = 16 floats (was 64 when the compiler hoisted all 32
// loads). Keeps whole-kernel register demand <=128 -> all-arch-VGPR, no AGPR
// shuttles around DPP/swizzle, higher occupancy. Loads stay L2-resident.
// ---------------------------------------------------------------------------
__device__ __forceinline__ void apply_diag(f2* s, const f2* __restrict__ base) {
    #pragma unroll
    for (int c = 0; c < 4; ++c) {
        f2 d[8];
        #pragma unroll
        for (int i = 0; i < 8; ++i) d[i] = base[(c * 8 + i) * 32];
        #pragma unroll
        for (int i = 0; i < 8; ++i) s[c * 8 + i] = cmul(d[i], s[c * 8 + i]);
        asm volatile("" ::: "memory");   // fence: don't hoist next chunk's loads
    }
}

// ---------------------------------------------------------------------------
// One wave simulates TWO batch elements: element = lane bit 5.
// Within a 32-lane half: storage k = (lane5 << 5) | loc.
//   qubits 0..4 <-> lane5 bits 4..0 ; qubits 5..9 <-> loc bits 4..0.
// 32 f2 amps per lane. All exchanges have mask < 32 (no bpermute anywhere).
// ---------------------------------------------------------------------------
__global__ __launch_bounds__(256, 4) void qsim_kernel(
        const float* __restrict__ inp,
        const float* __restrict__ ws,
        float* __restrict__ out,
        int B) {
    const int tid = threadIdx.x;
    const int lane = tid & 63;
    const int lane5 = lane & 31;
    const int e = lane >> 5;
    int b0 = ((blockIdx.x << 2) | (tid >> 6)) << 1;
    b0 = __builtin_amdgcn_readfirstlane(b0);
    if (b0 >= B) return;
    const int b = b0 + e;

    const float4* g0 = (const float4*)ws;
    const float* tw = ws + 64;
    const f2* dg = (const f2*)(ws + 256);

    // ---- hoist all 30 tangents into SGPRs (latency hidden under preamble) ----
    float tg[3 * NQ];
    #pragma unroll
    for (int g = 0; g < 3 * NQ; ++g)
        tg[g] = __int_as_float(__builtin_amdgcn_readfirstlane(__float_as_int(tw[g])));

    // ---- embedding fused with layer-0 Rot: lane w<10 of each half computes
    // qubit w of its element ----
    float x = (lane5 < NQ && b < B) ? inp[b * NQ + lane5] : 0.0f;
    float sn, cn;
    sincosf(0.5f * x, &sn, &cn);
    float a0r = 0.f, a0i = 0.f, a1r = 0.f, a1i = 0.f;
    if (lane5 < NQ) {
        float4 mm = g0[lane5];
        a0r = mm.x * cn + mm.z * sn;
        a0i = mm.y * cn + mm.w * sn;
        a1r = -mm.z * cn + mm.x * sn;
        a1i =  mm.w * cn - mm.y * sn;
    }
    // lane factor: qubits 0..4 <-> lane5 bits 4..0 (broadcast within half)
    f2 L;
    {
        float r0 = __shfl(a0r, 0, 32), i0 = __shfl(a0i, 0, 32);
        float r1 = __shfl(a1r, 0, 32), i1 = __shfl(a1i, 0, 32);
        int bit = (lane5 >> 4) & 1;
        L = ff(bit ? r1 : r0, bit ? i1 : i0);
    }
    #pragma unroll
    for (int w = 1; w < 5; ++w) {
        float r0 = __shfl(a0r, w, 32), i0 = __shfl(a0i, w, 32);
        float r1 = __shfl(a1r, w, 32), i1 = __shfl(a1i, w, 32);
        int bit = (lane5 >> (4 - w)) & 1;
        L = cmul(L, ff(bit ? r1 : r0, bit ? i1 : i0));
    }
    // local factors: qubits 5..9 <-> loc bits 4..0
    f2 A0[5], A1[5];
    #pragma unroll
    for (int j = 0; j < 5; ++j) {
        A0[j] = ff(__shfl(a0r, 5 + j, 32), __shfl(a0i, 5 + j, 32));
        A1[j] = ff(__shfl(a1r, 5 + j, 32), __shfl(a1i, 5 + j, 32));
    }
    f2 s[32];
    {
        f2 t01[4], t23[4], t3[8], lt[4];
        #pragma unroll
        for (int i = 0; i < 4; ++i) {
            t01[i] = cmul((i & 2) ? A1[0] : A0[0], (i & 1) ? A1[1] : A0[1]);
            t23[i] = cmul((i & 2) ? A1[2] : A0[2], (i & 1) ? A1[3] : A0[3]);
        }
        #pragma unroll
        for (int i = 0; i < 8; ++i)
            t3[i] = cmul(t23[i >> 1], (i & 1) ? A1[4] : A0[4]);
        #pragma unroll
        for (int i = 0; i < 4; ++i) lt[i] = cmul(L, t01[i]);
        #pragma unroll
        for (int i = 0; i < 32; ++i) s[i] = cmul(lt[i >> 3], t3[i & 7]);
    }

    // ---- D(phi1) ; RY1(t) ; D(w1+phi2)*P1 ; RY2(t) ; D(w2+phi3)*P2*P3 ; RY3(t) ----
    apply_diag(s, dg + lane5);
    Seq<1, 0>::run(s, tg, lane5);
    apply_diag(s, dg + 1024 + lane5);
    Seq<2, 0>::run(s, tg, lane5);
    apply_diag(s, dg + 2048 + lane5);
    Seq<3, 0>::run(s, tg, lane5);
    // omega(L3) diagonal dropped: killed by |amp|^2. Cosine products folded
    // into the diag tables -> state here is exactly the true state.

    // ---- measurement: local 32-pt WHT, then signed 5-level lane butterflies --
    float F[32];
    #pragma unroll
    for (int i = 0; i < 32; ++i) { f2 t = s[i] * s[i]; F[i] = t.x + t.y; }
    #pragma unroll
    for (int bit = 1; bit < 32; bit <<= 1) {
        #pragma unroll
        for (int i = 0; i < 32; ++i)
            if (!(i & bit)) { float u = F[i], v = F[i | bit]; F[i] = u + v; F[i | bit] = u - v; }
    }
    float ow = 0.0f;
    #pragma unroll
    for (int qi = 0; qi < NQ; ++qi) {
        const unsigned m = TAB.mr[qi];
        const unsigned ml = m & 31u, mh = m >> 5;
        float v = F[ml];
        if (mh) {
            unsigned sg = (unsigned)(__builtin_popcount((unsigned)lane5 & mh) & 1) << 31;
            v = __uint_as_float(__float_as_uint(v) ^ sg);
        }
        v += lxf<1u>(v); v += lxf<2u>(v); v += lxf<4u>(v);
        v += lxf<8u>(v); v += lxf<16u>(v);
        ow = (lane5 == qi) ? v : ow;
    }
    if (lane5 < NQ && b < B) out[b * NQ + lane5] = ow;
}

extern "C" void kernel_launch(void* const* d_in, const int* in_sizes, int n_in,
                              void* d_out, int out_size, void* d_ws, size_t ws_size,
                              hipStream_t stream) {
    const float* inp = (const float*)d_in[0];       // (B, NQ) float32
    const float* qw  = (const float*)d_in[1];       // (DEPTH, NQ, 3) float32
    float* out = (float*)d_out;                     // (B, NQ) float32
    float* ws  = (float*)d_ws;

    const int B = in_sizes[0] / NQ;

    qprep<<<1, 1024, 0, stream>>>(qw, ws);
    qsim_kernel<<<(B + 7) / 8, 256, 0, stream>>>(inp, ws, out, B);
}